// Round 6
// baseline (145.454 us; speedup 1.0000x reference)
//
#include <hip/hip_runtime.h>
#include <math.h>
#include <stdint.h>

#define INF_F 1.0e12f
#define NB 8
#define HW 512
#define PLANE (HW*HW)          // 262144
#define NPIX (NB*PLANE)        // 2097152
#define NBLK (16*16*NB)        // 2048 blocks

// Exact-but-slow per-pixel fallback (certificate m<=16 fails ~never for random
// masks; kept for unconditional exactness). Reads the mask from global memory.
__device__ __attribute__((noinline)) int exactRecompute(
    const float* __restrict__ outputs, const int* __restrict__ labels,
    int b, int z, int y, int x)
{
  const int base = (b*2 + 1)*PLANE;
  int m = 0x7fffffff;
  for (int ady = 0; ady < HW; ++ady) {
    if (ady*ady >= m) break;
    for (int sgn = 0; sgn < 2; ++sgn) {
      if (sgn && ady == 0) break;
      const int yy = sgn ? (y - ady) : (y + ady);
      if (yy < 0 || yy >= HW) continue;
      const int rb = base + yy*HW;
      const int a2 = ady*ady;
      for (int t = 0; t < HW; ++t) {
        const int c2 = a2 + t*t;
        if (c2 >= m) break;
        bool hit = false;
        const int xl = x - t, xr = x + t;
        if (xl >= 0)
          hit = (z == 0) ? (labels[rb + xl] <= 0) : !(outputs[rb + xl] > 0.5f);
        if (!hit && xr < HW)
          hit = (z == 0) ? (labels[rb + xr] <= 0) : !(outputs[rb + xr] > 0.5f);
        if (hit) { m = c2; break; }
      }
    }
  }
  return m;   // INT_MAX if no background anywhere
}

// -------- fully fused: bit-mask 2D EDT (both masks) + hd + dice + CE --------
// grid (16,16,8): 32x32 tile per block, 256 threads, 4 consecutive rows/thread.
// Ballot staging -> 48-bit row words; branch-free bounded scan |dy|<=3, exact
// when m<=16 (halo=8); rare exact fallback otherwise. Last finished block
// performs the final cross-block reduction (device-scope fence + counter).
__global__ __launch_bounds__(256) void fused_loss(
    const float* __restrict__ outputs, const int* __restrict__ labels,
    float* __restrict__ partials, unsigned int* __restrict__ counter,
    float* __restrict__ out)
{
  __shared__ uint64_t W[2][48];              // row bit-words, bit t = window col t
  __shared__ float  wredf[4][5];
  __shared__ double wredd[4][5];
  __shared__ int lastFlag;
  const int tid = threadIdx.x;
  const int wave = tid >> 6, lane = tid & 63;
  const int x0 = blockIdx.x * 32, y0 = blockIdx.y * 32, b = blockIdx.z;
  const int base1 = (b*2 + 1)*PLANE;

  // ---- ballot staging: each wave builds 24 of the 96 row-words ----
  {
    const int z    = wave >> 1;              // waves 0,1 -> gt ; 2,3 -> seg
    const int row0 = (wave & 1) * 24;
    const int xx   = x0 - 8 + lane;
    const bool xok = (lane < 48) && (xx >= 0) && (xx < HW);
    for (int r = 0; r < 24; ++r) {
      const int row = row0 + r;
      const int yy = y0 - 8 + row;
      bool pred = false;
      if (xok && yy >= 0 && yy < HW) {
        const int off = base1 + yy*HW + xx;
        pred = z ? !(outputs[off] > 0.5f) : (labels[off] <= 0);
      }
      const uint64_t word = __ballot(pred);
      if (lane == 0) W[z][row] = word;
    }
  }
  __syncthreads();

  // ---- branch-free per-pixel EDT: 4 consecutive rows per thread ----
  const int lx = tid & 31, lyb = tid >> 5;
  const int px = 8 + lx, sh = 63 - px;
  const int x = x0 + lx;
  const int ry0 = 8 + lyb*4;                 // window row of first pixel

  float d2m[2][4];
#pragma unroll
  for (int z = 0; z < 2; ++z) {
    const uint64_t* __restrict__ Wz = W[z];
    int rd2[10];                             // per-row nearest-dist^2 (63 cap)
#pragma unroll
    for (int j = 0; j < 10; ++j) {
      const uint64_t w = Wz[ry0 - 3 + j];
      const int dL = __builtin_clzll((w << sh) | 1ull);          // empty -> 63
      const int dR = __builtin_ctzll((w >> px) | (1ull << 63));  // empty -> 63
      const int d = min(dL, dR);
      rd2[j] = d*d;
    }
#pragma unroll
    for (int k = 0; k < 4; ++k) {
      int m = rd2[k+3];
      m = min(m, 1 + min(rd2[k+2], rd2[k+4]));
      m = min(m, 4 + min(rd2[k+1], rd2[k+5]));
      m = min(m, 9 + min(rd2[k+0], rd2[k+6]));
      float d2;
      if (__builtin_expect(m > 16, 0)) {     // certificate failed: exact fallback
        const int mr = exactRecompute(outputs, labels, b, z, y0 + lyb*4 + k, x);
        d2 = (mr == 0x7fffffff) ? INF_F : (float)mr;
      } else {
        d2 = (float)m;
      }
      d2m[z][k] = d2;
    }
  }

  // ---- fused hd / dice / CE (fp32 partials over 4 px) ----
  float s0 = 0, s1 = 0, s2 = 0, s3 = 0, s4 = 0;
#pragma unroll
  for (int k = 0; k < 4; ++k) {
    const int y = y0 + lyb*4 + k;
    const int off = base1 + y*HW + x;
    const float p1  = outputs[off];
    const float p0v = outputs[off - PLANE];
    const int   lv  = labels[off];
    const float labf = (lv > 0) ? 1.0f : 0.0f;
    const float dl = p1 - labf;
    s0 = fmaf(dl*dl, d2m[0][k] + d2m[1][k], s0);
    s1 = fmaf(p1, labf, s1);
    s2 = fmaf(p1, p1, s2);
    s3 += labf;
    const float mm  = fmaxf(p0v, p1);
    const float lse = mm + __logf(1.0f + __expf(fminf(p0v, p1) - mm));
    s4 += ((lv > 0) ? p1 : p0v) - lse;
  }

  for (int off = 32; off > 0; off >>= 1) {
    s0 += __shfl_down(s0, off, 64);
    s1 += __shfl_down(s1, off, 64);
    s2 += __shfl_down(s2, off, 64);
    s3 += __shfl_down(s3, off, 64);
    s4 += __shfl_down(s4, off, 64);
  }
  if (lane == 0) {
    wredf[wave][0] = s0; wredf[wave][1] = s1; wredf[wave][2] = s2;
    wredf[wave][3] = s3; wredf[wave][4] = s4;
  }
  __syncthreads();

  // tid 0 stores all 5 block partials itself, then release-fence + count.
  if (tid == 0) {
    const int bid = (blockIdx.z*16 + blockIdx.y)*16 + blockIdx.x;
#pragma unroll
    for (int q = 0; q < 5; ++q)
      partials[q*NBLK + bid] =
          wredf[0][q] + wredf[1][q] + wredf[2][q] + wredf[3][q];
    __threadfence();                          // release: partials -> device scope
    const unsigned int old = atomicAdd(counter, 1u);
    lastFlag = (old == (unsigned int)(NBLK - 1));
  }
  __syncthreads();

  // ---- last block: final reduction + loss ----
  if (lastFlag) {
    __threadfence();                          // acquire
    double t[5] = {0, 0, 0, 0, 0};
    for (int i = tid; i < NBLK; i += 256) {
#pragma unroll
      for (int q = 0; q < 5; ++q) t[q] += (double)partials[q*NBLK + i];
    }
    for (int off = 32; off > 0; off >>= 1) {
#pragma unroll
      for (int q = 0; q < 5; ++q) t[q] += __shfl_down(t[q], off, 64);
    }
    if (lane == 0) {
#pragma unroll
      for (int q = 0; q < 5; ++q) wredd[wave][q] = t[q];
    }
    __syncthreads();
    if (tid == 0) {
#pragma unroll
      for (int q = 0; q < 5; ++q)
        t[q] = wredd[0][q] + wredd[1][q] + wredd[2][q] + wredd[3][q];
      const double N = (double)NPIX;
      const double hd   = t[0] / N;
      const double ce   = -(t[4] / N);
      const double dice = 1.0 - (2.0*t[1] + 1e-6) / (t[2] + t[3] + 1e-6);
      out[0] = (float)(ce + dice + 0.5 * hd);   // LAM=1, 1-ALPHA=0.5
    }
  }
}

extern "C" void kernel_launch(void* const* d_in, const int* in_sizes, int n_in,
                              void* d_out, int out_size, void* d_ws, size_t ws_size,
                              hipStream_t stream)
{
  const float* outputs = (const float*)d_in[0];
  const int*   labels  = (const int*)d_in[1];
  float* partials = (float*)d_ws;                               // [5][NBLK] floats
  unsigned int* counter = (unsigned int*)((char*)d_ws + 5*NBLK*sizeof(float));

  hipMemsetAsync(counter, 0, 4, stream);
  fused_loss<<<dim3(16, 16, NB), 256, 0, stream>>>(outputs, labels,
                                                   partials, counter, (float*)d_out);
}

// Round 7
// 88.762 us; speedup vs baseline: 1.6387x; 1.6387x over previous
//
#include <hip/hip_runtime.h>
#include <math.h>
#include <stdint.h>

#define INF_F 1.0e12f
#define NB 8
#define HW 512
#define PLANE (HW*HW)          // 262144
#define NPIX (NB*PLANE)        // 2097152
#define TW 32                  // tile width  (x)
#define TH 64                  // tile height (y)
#define GX (HW/TW)             // 16
#define GY (HW/TH)             // 8
#define NBLK (GX*GY*NB)        // 1024 blocks
#define WROWS (TH + 16)        // 80 window rows (8-px halo top+bottom)

// Exact-but-slow per-pixel fallback (certificate m<=16 fails ~never for random
// masks; kept for unconditional exactness). Reads the mask from global memory.
__device__ __attribute__((noinline)) int exactRecompute(
    const float* __restrict__ outputs, const int* __restrict__ labels,
    int b, int z, int y, int x)
{
  const int base = (b*2 + 1)*PLANE;
  int m = 0x7fffffff;
  for (int ady = 0; ady < HW; ++ady) {
    if (ady*ady >= m) break;
    for (int sgn = 0; sgn < 2; ++sgn) {
      if (sgn && ady == 0) break;
      const int yy = sgn ? (y - ady) : (y + ady);
      if (yy < 0 || yy >= HW) continue;
      const int rb = base + yy*HW;
      const int a2 = ady*ady;
      for (int t = 0; t < HW; ++t) {
        const int c2 = a2 + t*t;
        if (c2 >= m) break;
        bool hit = false;
        const int xl = x - t, xr = x + t;
        if (xl >= 0)
          hit = (z == 0) ? (labels[rb + xl] <= 0) : !(outputs[rb + xl] > 0.5f);
        if (!hit && xr < HW)
          hit = (z == 0) ? (labels[rb + xr] <= 0) : !(outputs[rb + xr] > 0.5f);
        if (hit) { m = c2; break; }
      }
    }
  }
  return m;   // INT_MAX if no background anywhere
}

// -------- fully fused: bit-mask 2D EDT (both masks) + hd + dice + CE --------
// grid (16,8,8): 32x64 tile per block, 256 threads, 8 consecutive rows/thread.
// Staging writes 16-px bit-chunks as ushorts straight into the uint64 row
// words (little-endian overlay) -> one __syncthreads total. Branch-free
// bounded scan |dy|<=3, exact when m<=16 (halo=8); rare exact fallback.
__global__ __launch_bounds__(256) void fused_loss(
    const float* __restrict__ outputs, const int* __restrict__ labels,
    float* __restrict__ partials)
{
  __shared__ uint64_t W[2][WROWS];   // bit t = window col t (x = x0-8+t)
  __shared__ float wredf[4][5];
  const int tid = threadIdx.x;
  const int wave = tid >> 6, lane = tid & 63;
  const int x0 = blockIdx.x * TW, y0 = blockIdx.y * TH, b = blockIdx.z;
  const int base1 = (b*2 + 1)*PLANE;

  // ---- stage: 2 masks x 80 rows x 4 ushort chunks (ch 3 = zero pad) ----
  for (int idx = tid; idx < 2*WROWS*4; idx += 256) {
    const int z   = idx / (WROWS*4);
    const int rem = idx - z*(WROWS*4);
    const int row = rem >> 2, ch = rem & 3;
    const int yy = y0 - 8 + row;
    const int xs = x0 - 8 + ch*16;
    uint32_t bits = 0;
    if (ch < 3 && yy >= 0 && yy < HW) {
      const int rb = base1 + yy*HW;
      if (xs >= 0 && xs + 16 <= HW) {
        if (z == 0) {
          const int4* p = (const int4*)(labels + rb + xs);
          const int4 a = p[0], c = p[1], d = p[2], e = p[3];
          const int v[16] = {a.x,a.y,a.z,a.w, c.x,c.y,c.z,c.w,
                             d.x,d.y,d.z,d.w, e.x,e.y,e.z,e.w};
#pragma unroll
          for (int t = 0; t < 16; ++t) if (v[t] <= 0) bits |= (1u << t);
        } else {
          const float4* p = (const float4*)(outputs + rb + xs);
          const float4 a = p[0], c = p[1], d = p[2], e = p[3];
          const float v[16] = {a.x,a.y,a.z,a.w, c.x,c.y,c.z,c.w,
                               d.x,d.y,d.z,d.w, e.x,e.y,e.z,e.w};
#pragma unroll
          for (int t = 0; t < 16; ++t) if (!(v[t] > 0.5f)) bits |= (1u << t);
        }
      } else {
        for (int t = 0; t < 16; ++t) {
          const int xx = xs + t;
          if (xx < 0 || xx >= HW) continue;
          const bool bg = (z == 0) ? (labels[rb + xx] <= 0)
                                   : !(outputs[rb + xx] > 0.5f);
          if (bg) bits |= (1u << t);
        }
      }
    }
    ((unsigned short*)W)[idx] = (unsigned short)bits;  // LE overlay into words
  }
  __syncthreads();

  // ---- prefetch epilogue operands (hide latency behind EDT compute) ----
  const int lx = tid & 31, rg = tid >> 5;
  const int x = x0 + lx;
  const int ybase = y0 + rg*8;
  const int ry0 = 8 + rg*8;                  // window row of first pixel
  float p1v[8], p0v[8]; int lvv[8];
#pragma unroll
  for (int k = 0; k < 8; ++k) {
    const int off = base1 + (ybase + k)*HW + x;
    p1v[k] = outputs[off];
    p0v[k] = outputs[off - PLANE];
    lvv[k] = labels[off];
  }

  // ---- branch-free per-pixel EDT: 8 consecutive rows per thread ----
  const int px = 8 + lx, sh = 63 - px;
  float d2sum[8];
#pragma unroll
  for (int k = 0; k < 8; ++k) d2sum[k] = 0.0f;
#pragma unroll
  for (int z = 0; z < 2; ++z) {
    int rd2[14];                             // rows ry0-3 .. ry0+10
#pragma unroll
    for (int j = 0; j < 14; ++j) {
      const uint64_t w = W[z][ry0 - 3 + j];
      const int dL = __builtin_clzll((w << sh) | 1ull);          // empty -> 63
      const int dR = __builtin_ctzll((w >> px) | (1ull << 63));  // empty -> 63
      const int d = min(dL, dR);
      rd2[j] = d*d;
    }
#pragma unroll
    for (int k = 0; k < 8; ++k) {
      int m = rd2[k+3];
      m = min(m, 1 + min(rd2[k+2], rd2[k+4]));
      m = min(m, 4 + min(rd2[k+1], rd2[k+5]));
      m = min(m, 9 + min(rd2[k+0], rd2[k+6]));
      float d2;
      if (__builtin_expect(m > 16, 0)) {     // certificate failed: exact fallback
        const int mr = exactRecompute(outputs, labels, b, z, ybase + k, x);
        d2 = (mr == 0x7fffffff) ? INF_F : (float)mr;
      } else {
        d2 = (float)m;
      }
      d2sum[k] += d2;
    }
  }

  // ---- fused hd / dice / CE (fp32 partials over 8 px) ----
  float s0 = 0, s1 = 0, s2 = 0, s3 = 0, s4 = 0;
#pragma unroll
  for (int k = 0; k < 8; ++k) {
    const float p1  = p1v[k];
    const float p0f = p0v[k];
    const float labf = (lvv[k] > 0) ? 1.0f : 0.0f;
    const float dl = p1 - labf;
    s0 = fmaf(dl*dl, d2sum[k], s0);
    s1 = fmaf(p1, labf, s1);
    s2 = fmaf(p1, p1, s2);
    s3 += labf;
    const float mm  = fmaxf(p0f, p1);
    const float lse = mm + __logf(1.0f + __expf(fminf(p0f, p1) - mm));
    s4 += ((lvv[k] > 0) ? p1 : p0f) - lse;
  }

  for (int off = 32; off > 0; off >>= 1) {
    s0 += __shfl_down(s0, off, 64);
    s1 += __shfl_down(s1, off, 64);
    s2 += __shfl_down(s2, off, 64);
    s3 += __shfl_down(s3, off, 64);
    s4 += __shfl_down(s4, off, 64);
  }
  if (lane == 0) {
    wredf[wave][0] = s0; wredf[wave][1] = s1; wredf[wave][2] = s2;
    wredf[wave][3] = s3; wredf[wave][4] = s4;
  }
  __syncthreads();
  if (tid < 5) {
    const int bid = (blockIdx.z*GY + blockIdx.y)*GX + blockIdx.x;
    partials[tid*NBLK + bid] =
        wredf[0][tid] + wredf[1][tid] + wredf[2][tid] + wredf[3][tid];
  }
}

// ---------------- Finalize: reduce 1024 block-partials, compute loss --------
__global__ __launch_bounds__(256) void finalize(
    const float* __restrict__ partials, float* __restrict__ out)
{
  __shared__ double wred[4][5];
  const int tid = threadIdx.x;
  double s[5] = {0, 0, 0, 0, 0};
  for (int i = tid; i < NBLK; i += 256) {
#pragma unroll
    for (int q = 0; q < 5; ++q) s[q] += (double)partials[q*NBLK + i];
  }
  for (int off = 32; off > 0; off >>= 1) {
#pragma unroll
    for (int q = 0; q < 5; ++q) s[q] += __shfl_down(s[q], off, 64);
  }
  const int w = tid >> 6;
  if ((tid & 63) == 0) {
#pragma unroll
    for (int q = 0; q < 5; ++q) wred[w][q] = s[q];
  }
  __syncthreads();
  if (tid == 0) {
#pragma unroll
    for (int q = 0; q < 5; ++q) s[q] = wred[0][q] + wred[1][q] + wred[2][q] + wred[3][q];
    const double N = (double)NPIX;
    const double hd   = s[0] / N;
    const double ce   = -(s[4] / N);
    const double dice = 1.0 - (2.0*s[1] + 1e-6) / (s[2] + s[3] + 1e-6);
    out[0] = (float)(ce + dice + 0.5 * hd);   // LAM=1, 1-ALPHA=0.5
  }
}

extern "C" void kernel_launch(void* const* d_in, const int* in_sizes, int n_in,
                              void* d_out, int out_size, void* d_ws, size_t ws_size,
                              hipStream_t stream)
{
  const float* outputs = (const float*)d_in[0];
  const int*   labels  = (const int*)d_in[1];
  float* partials = (float*)d_ws;   // [5][NBLK] floats = 20 KB

  fused_loss<<<dim3(GX, GY, NB), 256, 0, stream>>>(outputs, labels, partials);
  finalize<<<1, 256, 0, stream>>>(partials, (float*)d_out);
}